// Round 6
// baseline (223.420 us; speedup 1.0000x reference)
//
#include <hip/hip_runtime.h>
#include <stdint.h>

typedef unsigned short u16;
typedef unsigned int u32;

#define NROWS 1024
#define DDIM  1024
#define SLEN  64
#define BATCH 64
#define VOCAB 32000
#define NBN2  125            // 256-wide column blocks
#define PAD_WORD 1

typedef __attribute__((ext_vector_type(4))) float f32x4;
typedef __attribute__((ext_vector_type(8))) short s16x8;

__device__ __forceinline__ u16 f2bf(float x) {
  union { float f; u32 u; } v; v.f = x;
  u32 r = v.u + 0x7FFF + ((v.u >> 16) & 1);   // RNE
  return (u16)(r >> 16);
}
__device__ __forceinline__ float bf2f(u16 x) {
  union { u32 u; float f; } v; v.u = ((u32)x) << 16;
  return v.f;
}
// packed pair f32->bf16, round-half-up (bias ≤ 0.5 ulp, fine at our tolerance)
__device__ __forceinline__ u32 pkbf(float a, float b) {
  union { float f; u32 u; } va, vb; va.f = a; vb.f = b;
  return ((va.u + 0x8000u) >> 16) | ((vb.u + 0x8000u) & 0xFFFF0000u);
}

// ---------------- kernel 1: p_copy + hidden -> bf16 ----------------
__global__ __launch_bounds__(256) void prep_kernel(
    const float* __restrict__ hidden, const float* __restrict__ w_copy,
    const float* __restrict__ b_copy, u16* __restrict__ hbf,
    float* __restrict__ pcopy)
{
  const int n = blockIdx.x;
  const int tid = threadIdx.x;
  float4 h = ((const float4*)(hidden + (size_t)n * DDIM))[tid];
  float4 w = ((const float4*)w_copy)[tid];
  ushort4 hb;
  hb.x = f2bf(h.x); hb.y = f2bf(h.y); hb.z = f2bf(h.z); hb.w = f2bf(h.w);
  ((ushort4*)(hbf + (size_t)n * DDIM))[tid] = hb;
  float d = h.x * w.x + h.y * w.y + h.z * w.z + h.w * w.w;
  #pragma unroll
  for (int m = 1; m < 64; m <<= 1) d += __shfl_xor(d, m);
  __shared__ float ws4[4];
  if ((tid & 63) == 0) ws4[tid >> 6] = d;
  __syncthreads();
  if (tid == 0) {
    float s = ws4[0] + ws4[1] + ws4[2] + ws4[3] + b_copy[0];
    pcopy[n] = 1.0f / (1.0f + __expf(-s));
  }
}

// -------- kernel 2: 256x256 bf16 GEMM, B read as f32 W directly (reg-staged
//          + inline cvt placed LATE in the tile), A via global_load_lds.
//          1 barrier / K-tile, counted vmcnt/lgkmcnt. exp epilogue. ----
__global__ __launch_bounds__(512, 2) void gemm_exp_kernel(
    const u16* __restrict__ A, const float* __restrict__ Wf,
    float* __restrict__ out, u16* __restrict__ ebf,
    float* __restrict__ partial, const int use_bf16)
{
  __shared__ u16 lA[2][16384];     // [dbuf][lo-half(8192) | hi-half]
  __shared__ u16 lB[2][16384];
  __shared__ float rowacc[4][256];

  const int tid  = threadIdx.x;
  const int lane = tid & 63;
  const int wid  = tid >> 6;        // 0..7
  const int wm   = wid >> 2;        // 0..1  (M)
  const int wn   = wid & 3;         // 0..3  (N)
  const int al   = lane & 15;
  const int ks   = lane >> 4;       // 0..3

  // bijective XCD-chunked swizzle for 500 blocks (q=62, r=4)
  const int orig = blockIdx.x;
  const int xcd  = orig & 7;
  const int idx  = orig >> 3;
  const int wg   = (xcd < 4 ? xcd * 63 : 252 + (xcd - 4) * 62) + idx;
  const int bm   = wg & 3;          // 4 M-blocks
  const int bn   = wg >> 2;         // 125 N-blocks

  const u16* Abase = A + (size_t)(bm * 256) * DDIM;

  // ---- A staging (global_load_lds, pre-swizzled source) ----
  const int s0  = wid * 128 + lane;      // 0..1023 (16B slots of a half-tile)
  const int rr0 = s0 >> 3;               // row within half (0..127)
  const int cs0 = (s0 & 7) ^ (rr0 & 7);  // pre-swizzled source slot

#define STAGEH(gptr, lptr) do { \
    __builtin_amdgcn_global_load_lds( \
        (const __attribute__((address_space(1))) u32*)((gptr) + (size_t)rr0 * DDIM + cs0 * 8), \
        (__attribute__((address_space(3))) u32*)((lptr) + s0 * 8), 16, 0, 0); \
    __builtin_amdgcn_global_load_lds( \
        (const __attribute__((address_space(1))) u32*)((gptr) + (size_t)(rr0 + 8) * DDIM + cs0 * 8), \
        (__attribute__((address_space(3))) u32*)((lptr) + s0 * 8 + 512), 16, 0, 0); \
  } while (0)
#define STAGE_A(lptr, kt) do { \
    STAGEH(Abase + (kt), (lptr)); \
    STAGEH(Abase + 128 * DDIM + (kt), (lptr) + 8192); \
  } while (0)

  // ---- B reg-staging: thread covers row (tid>>2) of each half, 16 f32 cols ----
  const int brow_st = tid >> 2;          // 0..127
  const int bk0     = (tid & 3) * 16;    // f32 col offset within 64-wide slab
  const float* Bsrc0 = Wf + (size_t)(bn * 256 + brow_st) * DDIM + bk0;
  const float* Bsrc1 = Bsrc0 + (size_t)128 * DDIM;
  f32x4 br[8];

#define ISSUE_B(kt) do { \
    br[0] = *(const f32x4*)(Bsrc0 + (kt));      \
    br[1] = *(const f32x4*)(Bsrc0 + (kt) + 4);  \
    br[2] = *(const f32x4*)(Bsrc0 + (kt) + 8);  \
    br[3] = *(const f32x4*)(Bsrc0 + (kt) + 12); \
    br[4] = *(const f32x4*)(Bsrc1 + (kt));      \
    br[5] = *(const f32x4*)(Bsrc1 + (kt) + 4);  \
    br[6] = *(const f32x4*)(Bsrc1 + (kt) + 8);  \
    br[7] = *(const f32x4*)(Bsrc1 + (kt) + 12); \
  } while (0)

  union pk8 { u32 w[4]; s16x8 v; };
#define CVT_WRITE_B(dstbase) do { \
    _Pragma("unroll") \
    for (int h_ = 0; h_ < 2; ++h_) { \
      _Pragma("unroll") \
      for (int j_ = 0; j_ < 2; ++j_) { \
        pk8 p_; \
        f32x4 f0_ = br[h_ * 4 + j_ * 2], f1_ = br[h_ * 4 + j_ * 2 + 1]; \
        p_.w[0] = pkbf(f0_.x, f0_.y); p_.w[1] = pkbf(f0_.z, f0_.w); \
        p_.w[2] = pkbf(f1_.x, f1_.y); p_.w[3] = pkbf(f1_.z, f1_.w); \
        const int sl_ = (((tid & 3) * 2 + j_) ^ (brow_st & 7)); \
        *(s16x8*)((dstbase) + h_ * 8192 + brow_st * 64 + sl_ * 8) = p_.v; \
      } \
    } \
  } while (0)

#define WL(n) do { asm volatile("s_waitcnt lgkmcnt(" #n ")" ::: "memory"); \
                   __builtin_amdgcn_sched_barrier(0); } while (0)
#define WV(n) do { asm volatile("s_waitcnt vmcnt(" #n ")" ::: "memory"); \
                   __builtin_amdgcn_sched_barrier(0); } while (0)
#define BAR() do { __builtin_amdgcn_sched_barrier(0); \
                   __builtin_amdgcn_s_barrier(); \
                   __builtin_amdgcn_sched_barrier(0); } while (0)

#define RD_ALO(buf) do { \
    _Pragma("unroll") \
    for (int mi = 0; mi < 4; ++mi) { \
      const u16* p_ = (buf) + wm * 8192 + (mi * 16 + al) * 64; \
      alo[mi][0] = *(const s16x8*)(p_ + (ks ^ (al & 7)) * 8); \
      alo[mi][1] = *(const s16x8*)(p_ + ((4 + ks) ^ (al & 7)) * 8); \
    } } while (0)
#define RD_AHI(buf) do { \
    _Pragma("unroll") \
    for (int mi = 0; mi < 4; ++mi) { \
      const u16* p_ = (buf) + wm * 8192 + (64 + mi * 16 + al) * 64; \
      ahi[mi][0] = *(const s16x8*)(p_ + (ks ^ (al & 7)) * 8); \
      ahi[mi][1] = *(const s16x8*)(p_ + ((4 + ks) ^ (al & 7)) * 8); \
    } } while (0)
#define RD_B0(buf) do { \
    _Pragma("unroll") \
    for (int ni = 0; ni < 2; ++ni) { \
      const u16* p_ = (buf) + (wn >> 1) * 8192 + ((wn & 1) * 64 + ni * 16 + al) * 64; \
      b0f[ni][0] = *(const s16x8*)(p_ + (ks ^ (al & 7)) * 8); \
      b0f[ni][1] = *(const s16x8*)(p_ + ((4 + ks) ^ (al & 7)) * 8); \
    } } while (0)
#define RD_B1(buf) do { \
    _Pragma("unroll") \
    for (int ni = 0; ni < 2; ++ni) { \
      const u16* p_ = (buf) + (wn >> 1) * 8192 + ((wn & 1) * 64 + 32 + ni * 16 + al) * 64; \
      b1f[ni][0] = *(const s16x8*)(p_ + (ks ^ (al & 7)) * 8); \
      b1f[ni][1] = *(const s16x8*)(p_ + ((4 + ks) ^ (al & 7)) * 8); \
    } } while (0)
#define MM(AF, BF, r0, c0) do { \
    __builtin_amdgcn_s_setprio(1); \
    _Pragma("unroll") \
    for (int mi = 0; mi < 4; ++mi) \
      _Pragma("unroll") \
      for (int ni = 0; ni < 2; ++ni) \
        _Pragma("unroll") \
        for (int kk = 0; kk < 2; ++kk) \
          acc[(r0) + mi][(c0) + ni] = __builtin_amdgcn_mfma_f32_16x16x32_bf16( \
              AF[mi][kk], BF[ni][kk], acc[(r0) + mi][(c0) + ni], 0, 0, 0); \
    __builtin_amdgcn_s_setprio(0); \
  } while (0)

  u16* lAc = &lA[0][0]; u16* lBc = &lB[0][0];
  u16* lAn = &lA[1][0]; u16* lBn = &lB[1][0];

  // ---- prologue ----
  ISSUE_B(0);                 // vm: 8
  STAGE_A(lAc, 0);            // vm: +4 = 12
  WV(4);                      // Bload(0) regs landed (A may fly)
  CVT_WRITE_B(lBc);
  ISSUE_B(64);                // Bload(1); vm: A(≤4) + 8
  WL(0);                      // ds_writes drained
  WV(8);                      // A(0) landed (Bload(1) remains)
  BAR();

  f32x4 acc[8][4];
  #pragma unroll
  for (int i = 0; i < 8; ++i)
    #pragma unroll
    for (int j = 0; j < 4; ++j)
      acc[i][j] = (f32x4){0.f, 0.f, 0.f, 0.f};

  s16x8 alo[4][2], ahi[4][2], b0f[2][2], b1f[2][2];

  for (int t = 0; t < 15; ++t) {
    RD_ALO(lAc); RD_B0(lBc); RD_B1(lBc);    // 16 ds_reads
    STAGE_A(lAn, (t + 1) * 64);             // 4 gload_lds (vm: 8 B + 4 A)
    WL(4);                                  // alo+b0 retired (b1 flying)
    MM(alo, b0f, 0, 0);
    RD_AHI(lAc);                            // +8 reads (outstanding: b1 4 + ahi 8)
    WL(8);                                  // b1 retired (ahi flying)
    MM(alo, b1f, 0, 2);
    WL(0);                                  // ahi ready
    MM(ahi, b0f, 4, 0);
    WV(4);                                  // B(t+1) regs landed (A stages remain)
    CVT_WRITE_B(lBn);                       // 4 ds_writes into next buf
    if (t < 14) ISSUE_B((t + 2) * 64);      // depth-1 tile prefetch
    WL(0);                                  // ds_writes drained
    if (t < 14) { WV(8); } else { WV(0); }  // A(t+1) landed (Bload(t+2) may fly)
    BAR();                                  // next buf fully ready for all waves
    MM(ahi, b1f, 4, 2);                     // reg-only, overlaps next-tile reads
    u16* tp = lAc; lAc = lAn; lAn = tp;
    tp = lBc; lBc = lBn; lBn = tp;
  }
  // ---- final tile t=15: reads + MFMA only ----
  RD_ALO(lAc); RD_B0(lBc); RD_B1(lBc);
  WL(4);
  MM(alo, b0f, 0, 0);
  RD_AHI(lAc);
  WL(8);
  MM(alo, b1f, 0, 2);
  WL(0);
  MM(ahi, b0f, 4, 0);
  MM(ahi, b1f, 4, 2);

#undef STAGEH
#undef STAGE_A
#undef ISSUE_B
#undef CVT_WRITE_B
#undef WL
#undef WV
#undef BAR

  // ---- epilogue: e = exp(logit), write (bf16 or f32), row-sums ----
  const int g = ks;                 // C/D: row = g*4 + j, col = lane&15
  float rsum[8][4];
  #pragma unroll
  for (int mi = 0; mi < 8; ++mi)
    #pragma unroll
    for (int j = 0; j < 4; ++j) rsum[mi][j] = 0.f;

  const size_t grow0 = (size_t)(bm * 256 + wm * 128);
  const int gcol0 = bn * 256 + wn * 64;
  #pragma unroll
  for (int mi = 0; mi < 8; ++mi) {
    const int rofs = (mi >> 2) * 64 + (mi & 3) * 16 + g * 4;
    #pragma unroll
    for (int j = 0; j < 4; ++j) {
      const size_t row = grow0 + rofs + j;
      #pragma unroll
      for (int ni = 0; ni < 4; ++ni) {
        const int col = gcol0 + (ni >> 1) * 32 + (ni & 1) * 16 + al;
        float e = __expf(acc[mi][ni][j]);
        if (col == PAD_WORD) e = 0.f;
        rsum[mi][j] += e;
        if (use_bf16) ebf[row * VOCAB + col] = f2bf(e);
        else          out[row * VOCAB + col] = e;
      }
    }
  }
  #pragma unroll
  for (int mi = 0; mi < 8; ++mi)
    #pragma unroll
    for (int j = 0; j < 4; ++j) {
      float v = rsum[mi][j];
      v += __shfl_xor(v, 1);
      v += __shfl_xor(v, 2);
      v += __shfl_xor(v, 4);
      v += __shfl_xor(v, 8);
      rsum[mi][j] = v;
    }
  if (al == 0) {
    #pragma unroll
    for (int mi = 0; mi < 8; ++mi)
      #pragma unroll
      for (int j = 0; j < 4; ++j)
        rowacc[wn][wm * 128 + (mi >> 2) * 64 + (mi & 3) * 16 + g * 4 + j] =
            rsum[mi][j];
  }
  __syncthreads();
  if (tid < 256)
    partial[(size_t)bn * NROWS + bm * 256 + tid] =
        rowacc[0][tid] + rowacc[1][tid] + rowacc[2][tid] + rowacc[3][tid];
}

// ---------------- kernel 3: reduce partials -> scale/ofs ----------------
__global__ __launch_bounds__(256) void rowsum_kernel(
    const float* __restrict__ partial, const float* __restrict__ pcopy,
    float* __restrict__ scale, float* __restrict__ ofs)
{
  const int n = blockIdx.x * 256 + threadIdx.x;
  if (n >= NROWS) return;
  float s = 0.f;
  for (int j = 0; j < NBN2; ++j) s += partial[(size_t)j * NROWS + n];
  const float p = pcopy[n];
  scale[n] = (1.0f - p) / s;
  ofs[n]   = (1.0f - p) * 1e-20f;
}

// ---------------- kernel 4a: normalize from bf16 exp -> f32 out ----------------
__global__ __launch_bounds__(256) void norm_bf16_kernel(
    const u16* __restrict__ ebf, float* __restrict__ out,
    const float* __restrict__ scale, const float* __restrict__ ofs)
{
  const int total8 = NROWS * VOCAB / 8;     // VOCAB/8 = 4000
  const int stride = gridDim.x * blockDim.x;
  for (int i = blockIdx.x * 256 + threadIdx.x; i < total8; i += stride) {
    const int n = i / (VOCAB / 8);
    ushort4 v0 = ((const ushort4*)ebf)[i * 2];
    ushort4 v1 = ((const ushort4*)ebf)[i * 2 + 1];
    const float sc = scale[n], of = ofs[n];
    float4 o0, o1;
    o0.x = bf2f(v0.x) * sc + of; o0.y = bf2f(v0.y) * sc + of;
    o0.z = bf2f(v0.z) * sc + of; o0.w = bf2f(v0.w) * sc + of;
    o1.x = bf2f(v1.x) * sc + of; o1.y = bf2f(v1.y) * sc + of;
    o1.z = bf2f(v1.z) * sc + of; o1.w = bf2f(v1.w) * sc + of;
    ((float4*)out)[i * 2]     = o0;
    ((float4*)out)[i * 2 + 1] = o1;
  }
}

// ---------------- kernel 4b: normalize f32 in place (fallback) ----------------
__global__ __launch_bounds__(256) void norm_kernel(
    float* __restrict__ out, const float* __restrict__ scale,
    const float* __restrict__ ofs)
{
  const int total4 = NROWS * VOCAB / 4;
  const int stride = gridDim.x * blockDim.x;
  for (int i = blockIdx.x * 256 + threadIdx.x; i < total4; i += stride) {
    const int n = i / (VOCAB / 4);
    float4* p = (float4*)out + i;
    float4 v = *p;
    const float sc = scale[n], of = ofs[n];
    v.x = v.x * sc + of;
    v.y = v.y * sc + of;
    v.z = v.z * sc + of;
    v.w = v.w * sc + of;
    *p = v;
  }
}

// ---------------- kernel 5: scatter-add copy mass ----------------
__global__ __launch_bounds__(256) void scatter_kernel(
    float* __restrict__ out, const float* __restrict__ attn,
    const int* __restrict__ src, const float* __restrict__ pcopy)
{
  const int t = blockIdx.x * 256 + threadIdx.x;   // 65536 total
  const int n = t >> 6;
  const int s = t & 63;
  const int b = n & (BATCH - 1);
  const int v = src[s * BATCH + b];
  const float w = pcopy[n] * attn[(size_t)n * SLEN + s];
  atomicAdd(out + (size_t)n * VOCAB + v, w);
}

extern "C" void kernel_launch(void* const* d_in, const int* in_sizes, int n_in,
                              void* d_out, int out_size, void* d_ws, size_t ws_size,
                              hipStream_t stream) {
  const float* hidden = (const float*)d_in[0];
  const float* attn   = (const float*)d_in[1];
  const int*   src    = (const int*)d_in[2];
  const float* W      = (const float*)d_in[3];
  const float* w_copy = (const float*)d_in[4];
  const float* b_copy = (const float*)d_in[5];
  float* out = (float*)d_out;

  char* ws = (char*)d_ws;
  u16*   hbf     = (u16*)ws;                                   //  2,097,152 B
  float* pcopy   = (float*)(ws + 2097152);                     //      4,096 B
  float* partial = (float*)(ws + 2101248);                     //  1,024,000 B
  float* scale   = (float*)(ws + 3125248);                     //      4,096 B
  float* ofs     = (float*)(ws + 3129344);                     //      4,096 B
  u16*   ebf     = (u16*)(ws + 3133440);                       // 65,536,000 B
  const size_t need_bf16 = 3133440ull + 65536000ull;
  const int use_bf16 = (ws_size >= need_bf16) ? 1 : 0;

  prep_kernel<<<NROWS, 256, 0, stream>>>(hidden, w_copy, b_copy, hbf, pcopy);
  gemm_exp_kernel<<<4 * NBN2, 512, 0, stream>>>(hbf, W, out, ebf, partial, use_bf16);
  rowsum_kernel<<<(NROWS + 255) / 256, 256, 0, stream>>>(partial, pcopy, scale, ofs);
  if (use_bf16)
    norm_bf16_kernel<<<2048, 256, 0, stream>>>(ebf, out, scale, ofs);
  else
    norm_kernel<<<2048, 256, 0, stream>>>(out, scale, ofs);
  scatter_kernel<<<NROWS * SLEN / 256, 256, 0, stream>>>(out, attn, src, pcopy);
}

// Round 7
// 222.798 us; speedup vs baseline: 1.0028x; 1.0028x over previous
//
#include <hip/hip_runtime.h>
#include <stdint.h>

typedef unsigned short u16;
typedef unsigned int u32;

#define NROWS 1024
#define DDIM  1024
#define SLEN  64
#define BATCH 64
#define VOCAB 32000
#define NBN2  125            // 256-wide column blocks
#define PAD_WORD 1

typedef __attribute__((ext_vector_type(4))) float f32x4;
typedef __attribute__((ext_vector_type(8))) short s16x8;

__device__ __forceinline__ u16 f2bf(float x) {
  union { float f; u32 u; } v; v.f = x;
  u32 r = v.u + 0x7FFF + ((v.u >> 16) & 1);   // RNE
  return (u16)(r >> 16);
}
__device__ __forceinline__ float bf2f(u16 x) {
  union { u32 u; float f; } v; v.u = ((u32)x) << 16;
  return v.f;
}
// packed pair f32->bf16, round-half-up (bias ≤ 0.5 ulp, fine at our tolerance)
__device__ __forceinline__ u32 pkbf(float a, float b) {
  union { float f; u32 u; } va, vb; va.f = a; vb.f = b;
  return ((va.u + 0x8000u) >> 16) | ((vb.u + 0x8000u) & 0xFFFF0000u);
}

// ---------------- kernel 1: p_copy + hidden -> bf16 ----------------
__global__ __launch_bounds__(256) void prep_kernel(
    const float* __restrict__ hidden, const float* __restrict__ w_copy,
    const float* __restrict__ b_copy, u16* __restrict__ hbf,
    float* __restrict__ pcopy)
{
  const int n = blockIdx.x;
  const int tid = threadIdx.x;
  float4 h = ((const float4*)(hidden + (size_t)n * DDIM))[tid];
  float4 w = ((const float4*)w_copy)[tid];
  ushort4 hb;
  hb.x = f2bf(h.x); hb.y = f2bf(h.y); hb.z = f2bf(h.z); hb.w = f2bf(h.w);
  ((ushort4*)(hbf + (size_t)n * DDIM))[tid] = hb;
  float d = h.x * w.x + h.y * w.y + h.z * w.z + h.w * w.w;
  #pragma unroll
  for (int m = 1; m < 64; m <<= 1) d += __shfl_xor(d, m);
  __shared__ float ws4[4];
  if ((tid & 63) == 0) ws4[tid >> 6] = d;
  __syncthreads();
  if (tid == 0) {
    float s = ws4[0] + ws4[1] + ws4[2] + ws4[3] + b_copy[0];
    pcopy[n] = 1.0f / (1.0f + __expf(-s));
  }
}

// -------- kernel 2: 256x256 bf16 GEMM, B read as f32 W directly (reg-staged
//          + inline cvt placed LATE in the tile, full-tile latency cover),
//          A via global_load_lds. 1 barrier / K-tile. exp epilogue.
//          NOTE: launch_bounds(512) WITHOUT min-waves — LDS (132KB) already
//          caps at 1 block/CU; a VGPR cap of 128 only forces spills. ----
__global__ __launch_bounds__(512) void gemm_exp_kernel(
    const u16* __restrict__ A, const float* __restrict__ Wf,
    float* __restrict__ out, u16* __restrict__ ebf,
    float* __restrict__ partial, const int use_bf16)
{
  __shared__ u16 lA[2][16384];     // [dbuf][lo-half(8192) | hi-half]
  __shared__ u16 lB[2][16384];
  __shared__ float rowacc[4][256];

  const int tid  = threadIdx.x;
  const int lane = tid & 63;
  const int wid  = tid >> 6;        // 0..7
  const int wm   = wid >> 2;        // 0..1  (M)
  const int wn   = wid & 3;         // 0..3  (N)
  const int al   = lane & 15;
  const int ks   = lane >> 4;       // 0..3

  // bijective XCD-chunked swizzle for 500 blocks (q=62, r=4)
  const int orig = blockIdx.x;
  const int xcd  = orig & 7;
  const int idx  = orig >> 3;
  const int wg   = (xcd < 4 ? xcd * 63 : 252 + (xcd - 4) * 62) + idx;
  const int bm   = wg & 3;          // 4 M-blocks
  const int bn   = wg >> 2;         // 125 N-blocks

  const u16* Abase = A + (size_t)(bm * 256) * DDIM;

  // ---- A staging (global_load_lds, pre-swizzled source) ----
  const int s0  = wid * 128 + lane;      // 0..1023 (16B slots of a half-tile)
  const int rr0 = s0 >> 3;               // row within half (0..127)
  const int cs0 = (s0 & 7) ^ (rr0 & 7);  // pre-swizzled source slot

#define STAGEH(gptr, lptr) do { \
    __builtin_amdgcn_global_load_lds( \
        (const __attribute__((address_space(1))) u32*)((gptr) + (size_t)rr0 * DDIM + cs0 * 8), \
        (__attribute__((address_space(3))) u32*)((lptr) + s0 * 8), 16, 0, 0); \
    __builtin_amdgcn_global_load_lds( \
        (const __attribute__((address_space(1))) u32*)((gptr) + (size_t)(rr0 + 8) * DDIM + cs0 * 8), \
        (__attribute__((address_space(3))) u32*)((lptr) + s0 * 8 + 512), 16, 0, 0); \
  } while (0)
#define STAGE_A(lptr, kt) do { \
    STAGEH(Abase + (kt), (lptr)); \
    STAGEH(Abase + 128 * DDIM + (kt), (lptr) + 8192); \
  } while (0)

  // ---- B reg-staging: thread covers row (tid>>2) of each half, 16 f32 cols ----
  const int brow_st = tid >> 2;          // 0..127
  const int bk0     = (tid & 3) * 16;    // f32 col offset within 64-wide slab
  const float* Bsrc0 = Wf + (size_t)(bn * 256 + brow_st) * DDIM + bk0;
  const float* Bsrc1 = Bsrc0 + (size_t)128 * DDIM;
  f32x4 br[8];

#define ISSUE_B(kt) do { \
    br[0] = *(const f32x4*)(Bsrc0 + (kt));      \
    br[1] = *(const f32x4*)(Bsrc0 + (kt) + 4);  \
    br[2] = *(const f32x4*)(Bsrc0 + (kt) + 8);  \
    br[3] = *(const f32x4*)(Bsrc0 + (kt) + 12); \
    br[4] = *(const f32x4*)(Bsrc1 + (kt));      \
    br[5] = *(const f32x4*)(Bsrc1 + (kt) + 4);  \
    br[6] = *(const f32x4*)(Bsrc1 + (kt) + 8);  \
    br[7] = *(const f32x4*)(Bsrc1 + (kt) + 12); \
  } while (0)

  union pk8 { u32 w[4]; s16x8 v; };
#define CVT_WRITE_B(dstbase) do { \
    _Pragma("unroll") \
    for (int h_ = 0; h_ < 2; ++h_) { \
      _Pragma("unroll") \
      for (int j_ = 0; j_ < 2; ++j_) { \
        pk8 p_; \
        f32x4 f0_ = br[h_ * 4 + j_ * 2], f1_ = br[h_ * 4 + j_ * 2 + 1]; \
        p_.w[0] = pkbf(f0_.x, f0_.y); p_.w[1] = pkbf(f0_.z, f0_.w); \
        p_.w[2] = pkbf(f1_.x, f1_.y); p_.w[3] = pkbf(f1_.z, f1_.w); \
        const int sl_ = (((tid & 3) * 2 + j_) ^ (brow_st & 7)); \
        *(s16x8*)((dstbase) + h_ * 8192 + brow_st * 64 + sl_ * 8) = p_.v; \
      } \
    } \
  } while (0)

#define WL(n) do { asm volatile("s_waitcnt lgkmcnt(" #n ")" ::: "memory"); \
                   __builtin_amdgcn_sched_barrier(0); } while (0)
#define WV(n) do { asm volatile("s_waitcnt vmcnt(" #n ")" ::: "memory"); \
                   __builtin_amdgcn_sched_barrier(0); } while (0)
#define BAR() do { __builtin_amdgcn_sched_barrier(0); \
                   __builtin_amdgcn_s_barrier(); \
                   __builtin_amdgcn_sched_barrier(0); } while (0)

#define RD_ALO(buf) do { \
    _Pragma("unroll") \
    for (int mi = 0; mi < 4; ++mi) { \
      const u16* p_ = (buf) + wm * 8192 + (mi * 16 + al) * 64; \
      alo[mi][0] = *(const s16x8*)(p_ + (ks ^ (al & 7)) * 8); \
      alo[mi][1] = *(const s16x8*)(p_ + ((4 + ks) ^ (al & 7)) * 8); \
    } } while (0)
#define RD_AHI(buf) do { \
    _Pragma("unroll") \
    for (int mi = 0; mi < 4; ++mi) { \
      const u16* p_ = (buf) + wm * 8192 + (64 + mi * 16 + al) * 64; \
      ahi[mi][0] = *(const s16x8*)(p_ + (ks ^ (al & 7)) * 8); \
      ahi[mi][1] = *(const s16x8*)(p_ + ((4 + ks) ^ (al & 7)) * 8); \
    } } while (0)
#define RD_B0(buf) do { \
    _Pragma("unroll") \
    for (int ni = 0; ni < 2; ++ni) { \
      const u16* p_ = (buf) + (wn >> 1) * 8192 + ((wn & 1) * 64 + ni * 16 + al) * 64; \
      b0f[ni][0] = *(const s16x8*)(p_ + (ks ^ (al & 7)) * 8); \
      b0f[ni][1] = *(const s16x8*)(p_ + ((4 + ks) ^ (al & 7)) * 8); \
    } } while (0)
#define RD_B1(buf) do { \
    _Pragma("unroll") \
    for (int ni = 0; ni < 2; ++ni) { \
      const u16* p_ = (buf) + (wn >> 1) * 8192 + ((wn & 1) * 64 + 32 + ni * 16 + al) * 64; \
      b1f[ni][0] = *(const s16x8*)(p_ + (ks ^ (al & 7)) * 8); \
      b1f[ni][1] = *(const s16x8*)(p_ + ((4 + ks) ^ (al & 7)) * 8); \
    } } while (0)
#define MM(AF, BF, r0, c0) do { \
    __builtin_amdgcn_s_setprio(1); \
    _Pragma("unroll") \
    for (int mi = 0; mi < 4; ++mi) \
      _Pragma("unroll") \
      for (int ni = 0; ni < 2; ++ni) \
        _Pragma("unroll") \
        for (int kk = 0; kk < 2; ++kk) \
          acc[(r0) + mi][(c0) + ni] = __builtin_amdgcn_mfma_f32_16x16x32_bf16( \
              AF[mi][kk], BF[ni][kk], acc[(r0) + mi][(c0) + ni], 0, 0, 0); \
    __builtin_amdgcn_s_setprio(0); \
  } while (0)

  u16* lAc = &lA[0][0]; u16* lBc = &lB[0][0];
  u16* lAn = &lA[1][0]; u16* lBn = &lB[1][0];

  // ---- prologue ----
  ISSUE_B(0);                 // vm: 8
  STAGE_A(lAc, 0);            // vm: +4 = 12
  WV(4);                      // Bload(0) regs landed (A may fly)
  CVT_WRITE_B(lBc);
  ISSUE_B(64);                // Bload(1); vm: A(≤4) + 8
  WL(0);                      // ds_writes drained
  WV(8);                      // A(0) landed (Bload(1) remains)
  BAR();

  f32x4 acc[8][4];
  #pragma unroll
  for (int i = 0; i < 8; ++i)
    #pragma unroll
    for (int j = 0; j < 4; ++j)
      acc[i][j] = (f32x4){0.f, 0.f, 0.f, 0.f};

  s16x8 alo[4][2], ahi[4][2], b0f[2][2], b1f[2][2];

  for (int t = 0; t < 15; ++t) {
    RD_ALO(lAc); RD_B0(lBc); RD_B1(lBc);    // 16 ds_reads
    STAGE_A(lAn, (t + 1) * 64);             // 4 gload_lds (vm: 8 B + 4 A)
    WL(4);                                  // alo+b0 retired (b1 flying)
    MM(alo, b0f, 0, 0);
    RD_AHI(lAc);                            // +8 reads (outstanding: b1 4 + ahi 8)
    WL(8);                                  // b1 retired (ahi flying)
    MM(alo, b1f, 0, 2);
    WL(0);                                  // ahi ready
    MM(ahi, b0f, 4, 0);
    WV(4);                                  // B(t+1) regs landed (A stages remain)
    CVT_WRITE_B(lBn);                       // 4 ds_writes into next buf
    if (t < 14) ISSUE_B((t + 2) * 64);      // depth-1 tile prefetch
    WL(0);                                  // ds_writes drained
    if (t < 14) { WV(8); } else { WV(0); }  // A(t+1) landed (Bload(t+2) may fly)
    BAR();                                  // next buf fully ready for all waves
    MM(ahi, b1f, 4, 2);                     // reg-only, overlaps next-tile reads
    u16* tp = lAc; lAc = lAn; lAn = tp;
    tp = lBc; lBc = lBn; lBn = tp;
  }
  // ---- final tile t=15: reads + MFMA only ----
  RD_ALO(lAc); RD_B0(lBc); RD_B1(lBc);
  WL(4);
  MM(alo, b0f, 0, 0);
  RD_AHI(lAc);
  WL(8);
  MM(alo, b1f, 0, 2);
  WL(0);
  MM(ahi, b0f, 4, 0);
  MM(ahi, b1f, 4, 2);

#undef STAGEH
#undef STAGE_A
#undef ISSUE_B
#undef CVT_WRITE_B
#undef WL
#undef WV
#undef BAR

  // ---- epilogue: e = exp(logit), write (bf16 or f32), row-sums ----
  const int g = ks;                 // C/D: row = g*4 + j, col = lane&15
  float rsum[8][4];
  #pragma unroll
  for (int mi = 0; mi < 8; ++mi)
    #pragma unroll
    for (int j = 0; j < 4; ++j) rsum[mi][j] = 0.f;

  const size_t grow0 = (size_t)(bm * 256 + wm * 128);
  const int gcol0 = bn * 256 + wn * 64;
  #pragma unroll
  for (int mi = 0; mi < 8; ++mi) {
    const int rofs = (mi >> 2) * 64 + (mi & 3) * 16 + g * 4;
    #pragma unroll
    for (int j = 0; j < 4; ++j) {
      const size_t row = grow0 + rofs + j;
      #pragma unroll
      for (int ni = 0; ni < 4; ++ni) {
        const int col = gcol0 + (ni >> 1) * 32 + (ni & 1) * 16 + al;
        float e = __expf(acc[mi][ni][j]);
        if (col == PAD_WORD) e = 0.f;
        rsum[mi][j] += e;
        if (use_bf16) ebf[row * VOCAB + col] = f2bf(e);
        else          out[row * VOCAB + col] = e;
      }
    }
  }
  #pragma unroll
  for (int mi = 0; mi < 8; ++mi)
    #pragma unroll
    for (int j = 0; j < 4; ++j) {
      float v = rsum[mi][j];
      v += __shfl_xor(v, 1);
      v += __shfl_xor(v, 2);
      v += __shfl_xor(v, 4);
      v += __shfl_xor(v, 8);
      rsum[mi][j] = v;
    }
  if (al == 0) {
    #pragma unroll
    for (int mi = 0; mi < 8; ++mi)
      #pragma unroll
      for (int j = 0; j < 4; ++j)
        rowacc[wn][wm * 128 + (mi >> 2) * 64 + (mi & 3) * 16 + g * 4 + j] =
            rsum[mi][j];
  }
  __syncthreads();
  if (tid < 256)
    partial[(size_t)bn * NROWS + bm * 256 + tid] =
        rowacc[0][tid] + rowacc[1][tid] + rowacc[2][tid] + rowacc[3][tid];
}

// ---------------- kernel 3: reduce partials -> scale/ofs ----------------
__global__ __launch_bounds__(256) void rowsum_kernel(
    const float* __restrict__ partial, const float* __restrict__ pcopy,
    float* __restrict__ scale, float* __restrict__ ofs)
{
  const int n = blockIdx.x * 256 + threadIdx.x;
  if (n >= NROWS) return;
  float s = 0.f;
  for (int j = 0; j < NBN2; ++j) s += partial[(size_t)j * NROWS + n];
  const float p = pcopy[n];
  scale[n] = (1.0f - p) / s;
  ofs[n]   = (1.0f - p) * 1e-20f;
}

// ---------------- kernel 4a: normalize from bf16 exp -> f32 out ----------------
__global__ __launch_bounds__(256) void norm_bf16_kernel(
    const u16* __restrict__ ebf, float* __restrict__ out,
    const float* __restrict__ scale, const float* __restrict__ ofs)
{
  const int total8 = NROWS * VOCAB / 8;     // VOCAB/8 = 4000
  const int stride = gridDim.x * blockDim.x;
  for (int i = blockIdx.x * 256 + threadIdx.x; i < total8; i += stride) {
    const int n = i / (VOCAB / 8);
    ushort4 v0 = ((const ushort4*)ebf)[i * 2];
    ushort4 v1 = ((const ushort4*)ebf)[i * 2 + 1];
    const float sc = scale[n], of = ofs[n];
    float4 o0, o1;
    o0.x = bf2f(v0.x) * sc + of; o0.y = bf2f(v0.y) * sc + of;
    o0.z = bf2f(v0.z) * sc + of; o0.w = bf2f(v0.w) * sc + of;
    o1.x = bf2f(v1.x) * sc + of; o1.y = bf2f(v1.y) * sc + of;
    o1.z = bf2f(v1.z) * sc + of; o1.w = bf2f(v1.w) * sc + of;
    ((float4*)out)[i * 2]     = o0;
    ((float4*)out)[i * 2 + 1] = o1;
  }
}

// ---------------- kernel 4b: normalize f32 in place (fallback) ----------------
__global__ __launch_bounds__(256) void norm_kernel(
    float* __restrict__ out, const float* __restrict__ scale,
    const float* __restrict__ ofs)
{
  const int total4 = NROWS * VOCAB / 4;
  const int stride = gridDim.x * blockDim.x;
  for (int i = blockIdx.x * 256 + threadIdx.x; i < total4; i += stride) {
    const int n = i / (VOCAB / 4);
    float4* p = (float4*)out + i;
    float4 v = *p;
    const float sc = scale[n], of = ofs[n];
    v.x = v.x * sc + of;
    v.y = v.y * sc + of;
    v.z = v.z * sc + of;
    v.w = v.w * sc + of;
    *p = v;
  }
}

// ---------------- kernel 5: scatter-add copy mass ----------------
__global__ __launch_bounds__(256) void scatter_kernel(
    float* __restrict__ out, const float* __restrict__ attn,
    const int* __restrict__ src, const float* __restrict__ pcopy)
{
  const int t = blockIdx.x * 256 + threadIdx.x;   // 65536 total
  const int n = t >> 6;
  const int s = t & 63;
  const int b = n & (BATCH - 1);
  const int v = src[s * BATCH + b];
  const float w = pcopy[n] * attn[(size_t)n * SLEN + s];
  atomicAdd(out + (size_t)n * VOCAB + v, w);
}

extern "C" void kernel_launch(void* const* d_in, const int* in_sizes, int n_in,
                              void* d_out, int out_size, void* d_ws, size_t ws_size,
                              hipStream_t stream) {
  const float* hidden = (const float*)d_in[0];
  const float* attn   = (const float*)d_in[1];
  const int*   src    = (const int*)d_in[2];
  const float* W      = (const float*)d_in[3];
  const float* w_copy = (const float*)d_in[4];
  const float* b_copy = (const float*)d_in[5];
  float* out = (float*)d_out;

  char* ws = (char*)d_ws;
  u16*   hbf     = (u16*)ws;                                   //  2,097,152 B
  float* pcopy   = (float*)(ws + 2097152);                     //      4,096 B
  float* partial = (float*)(ws + 2101248);                     //  1,024,000 B
  float* scale   = (float*)(ws + 3125248);                     //      4,096 B
  float* ofs     = (float*)(ws + 3129344);                     //      4,096 B
  u16*   ebf     = (u16*)(ws + 3133440);                       // 65,536,000 B
  const size_t need_bf16 = 3133440ull + 65536000ull;
  const int use_bf16 = (ws_size >= need_bf16) ? 1 : 0;

  prep_kernel<<<NROWS, 256, 0, stream>>>(hidden, w_copy, b_copy, hbf, pcopy);
  gemm_exp_kernel<<<4 * NBN2, 512, 0, stream>>>(hbf, W, out, ebf, partial, use_bf16);
  rowsum_kernel<<<(NROWS + 255) / 256, 256, 0, stream>>>(partial, pcopy, scale, ofs);
  if (use_bf16)
    norm_bf16_kernel<<<2048, 256, 0, stream>>>(ebf, out, scale, ofs);
  else
    norm_kernel<<<2048, 256, 0, stream>>>(out, scale, ofs);
  scatter_kernel<<<NROWS * SLEN / 256, 256, 0, stream>>>(out, attn, src, pcopy);
}